// Round 1
// baseline (343.984 us; speedup 1.0000x reference)
//
#include <hip/hip_runtime.h>

#define H 16
#define NSEQ 2048
#define HD 64
#define CDIM 1024

typedef __attribute__((ext_vector_type(8))) short s8v;
typedef __attribute__((ext_vector_type(4))) float f4v;

__device__ __forceinline__ short f2bf(float f) {
  union { float f; unsigned u; } x; x.f = f;
  unsigned r = (x.u + 0x7fffu + ((x.u >> 16) & 1u)) >> 16;
  return (short)r;
}

// ---------------- fp32 -> bf16 conversion ----------------
__global__ __launch_bounds__(256) void cvt_kernel(const float* __restrict__ in,
                                                  short* __restrict__ out, int n4) {
  int i = blockIdx.x * 256 + threadIdx.x;
  if (i < n4) {
    float4 f = ((const float4*)in)[i];
    short4 s;
    s.x = f2bf(f.x); s.y = f2bf(f.y); s.z = f2bf(f.z); s.w = f2bf(f.w);
    ((short4*)out)[i] = s;
  }
}

// ---------------- gate MLP: gate[b,n] = sigmoid(sum_j g2w[j]*relu(m*g1w[j]+g1b[j]) + g2b) ----------------
__global__ __launch_bounds__(256) void gate_kernel(const float* __restrict__ mask,
    const float* __restrict__ g1w, const float* __restrict__ g1b,
    const float* __restrict__ g2w, const float* __restrict__ g2b,
    float* __restrict__ gate) {
  int i = blockIdx.x * 256 + threadIdx.x;  // 4096 = B*N
  float m = mask[i];
  float acc = 0.f;
  for (int j = 0; j < 256; j++) {
    float h = m * g1w[j] + g1b[j];
    h = fmaxf(h, 0.f);
    acc += g2w[j] * h;
  }
  gate[i] = 1.f / (1.f + __expf(-(acc + g2b[0])));
}

// ---------------- QKV GEMM: C[4096,3072] = Xbf[4096,1024] @ Wbf[3072,1024]^T + bias ----------------
// epilogue scatters into q/k/v (B,H,N,HD) bf16, q pre-scaled by 1/8
__global__ __launch_bounds__(256) void gemm_qkv(const short* __restrict__ X,
    const short* __restrict__ W, const float* __restrict__ bias,
    short* __restrict__ qws, short* __restrict__ kws, short* __restrict__ vws) {
  __shared__ __align__(16) short At[128][40];
  __shared__ __align__(16) short Bt[128][40];
  const int K = CDIM;
  int tid = threadIdx.x;
  int lane = tid & 63, w = tid >> 6;
  int quad = lane >> 4, l15 = lane & 15;
  int wm = w >> 1, wn = w & 1;
  long rowBase = (long)blockIdx.y * 128;
  long colBase = (long)blockIdx.x * 128;
  int r0 = tid >> 2, cg0 = (tid & 3) * 8;
  const f4v fz = {0.f, 0.f, 0.f, 0.f};
  f4v acc[4][4];
#pragma unroll
  for (int i = 0; i < 4; i++)
#pragma unroll
    for (int j = 0; j < 4; j++) acc[i][j] = fz;

  for (int k0 = 0; k0 < K; k0 += 32) {
    __syncthreads();
    *(uint4*)&At[r0][cg0]      = *(const uint4*)&X[(rowBase + r0) * K + k0 + cg0];
    *(uint4*)&At[r0 + 64][cg0] = *(const uint4*)&X[(rowBase + r0 + 64) * K + k0 + cg0];
    *(uint4*)&Bt[r0][cg0]      = *(const uint4*)&W[(colBase + r0) * K + k0 + cg0];
    *(uint4*)&Bt[r0 + 64][cg0] = *(const uint4*)&W[(colBase + r0 + 64) * K + k0 + cg0];
    __syncthreads();
    s8v a[4], b[4];
#pragma unroll
    for (int mi = 0; mi < 4; mi++) a[mi] = *(const s8v*)&At[wm * 64 + mi * 16 + l15][quad * 8];
#pragma unroll
    for (int ni = 0; ni < 4; ni++) b[ni] = *(const s8v*)&Bt[wn * 64 + ni * 16 + l15][quad * 8];
#pragma unroll
    for (int mi = 0; mi < 4; mi++)
#pragma unroll
      for (int ni = 0; ni < 4; ni++)
        acc[mi][ni] = __builtin_amdgcn_mfma_f32_16x16x32_bf16(a[mi], b[ni], acc[mi][ni], 0, 0, 0);
  }
#pragma unroll
  for (int mi = 0; mi < 4; mi++) {
    int row = (int)rowBase + wm * 64 + mi * 16 + quad * 4;
#pragma unroll
    for (int ni = 0; ni < 4; ni++) {
      int col = (int)colBase + wn * 64 + ni * 16 + l15;
      int which = col >> 10, cc = col & 1023;
      int hh = cc >> 6, dd = cc & 63;
      float bcol = bias[col];
#pragma unroll
      for (int r = 0; r < 4; r++) {
        int rw = row + r;
        int bb = rw >> 11, nn = rw & 2047;
        int idx = ((bb * H + hh) * NSEQ + nn) * HD + dd;
        float v = acc[mi][ni][r] + bcol;
        if (which == 0) qws[idx] = f2bf(v * 0.125f);
        else if (which == 1) kws[idx] = f2bf(v);
        else vws[idx] = f2bf(v);
      }
    }
  }
}

// ---------------- Proj GEMM: out[4096,1024] = Abf[4096,1024] @ Wbf[1024,1024]^T + bias (fp32 out) ----------------
__global__ __launch_bounds__(256) void gemm_proj(const short* __restrict__ X,
    const short* __restrict__ W, const float* __restrict__ bias, float* __restrict__ out) {
  __shared__ __align__(16) short At[128][40];
  __shared__ __align__(16) short Bt[128][40];
  const int K = CDIM;
  int tid = threadIdx.x;
  int lane = tid & 63, w = tid >> 6;
  int quad = lane >> 4, l15 = lane & 15;
  int wm = w >> 1, wn = w & 1;
  long rowBase = (long)blockIdx.y * 128;
  long colBase = (long)blockIdx.x * 128;
  int r0 = tid >> 2, cg0 = (tid & 3) * 8;
  const f4v fz = {0.f, 0.f, 0.f, 0.f};
  f4v acc[4][4];
#pragma unroll
  for (int i = 0; i < 4; i++)
#pragma unroll
    for (int j = 0; j < 4; j++) acc[i][j] = fz;

  for (int k0 = 0; k0 < K; k0 += 32) {
    __syncthreads();
    *(uint4*)&At[r0][cg0]      = *(const uint4*)&X[(rowBase + r0) * K + k0 + cg0];
    *(uint4*)&At[r0 + 64][cg0] = *(const uint4*)&X[(rowBase + r0 + 64) * K + k0 + cg0];
    *(uint4*)&Bt[r0][cg0]      = *(const uint4*)&W[(colBase + r0) * K + k0 + cg0];
    *(uint4*)&Bt[r0 + 64][cg0] = *(const uint4*)&W[(colBase + r0 + 64) * K + k0 + cg0];
    __syncthreads();
    s8v a[4], b[4];
#pragma unroll
    for (int mi = 0; mi < 4; mi++) a[mi] = *(const s8v*)&At[wm * 64 + mi * 16 + l15][quad * 8];
#pragma unroll
    for (int ni = 0; ni < 4; ni++) b[ni] = *(const s8v*)&Bt[wn * 64 + ni * 16 + l15][quad * 8];
#pragma unroll
    for (int mi = 0; mi < 4; mi++)
#pragma unroll
      for (int ni = 0; ni < 4; ni++)
        acc[mi][ni] = __builtin_amdgcn_mfma_f32_16x16x32_bf16(a[mi], b[ni], acc[mi][ni], 0, 0, 0);
  }
#pragma unroll
  for (int mi = 0; mi < 4; mi++) {
    int row = (int)rowBase + wm * 64 + mi * 16 + quad * 4;
#pragma unroll
    for (int ni = 0; ni < 4; ni++) {
      int col = (int)colBase + wn * 64 + ni * 16 + l15;
      float bcol = bias[col];
#pragma unroll
      for (int r = 0; r < 4; r++)
        out[(long)(row + r) * CDIM + col] = acc[mi][ni][r] + bcol;
    }
  }
}

// ---------------- Flash attention: one block per (b,h,64-row q-tile), BK=32 ----------------
__global__ __launch_bounds__(256) void attn_kernel(const short* __restrict__ qws,
    const short* __restrict__ kws, const short* __restrict__ vws,
    const float* __restrict__ gate, short* __restrict__ attn_out) {
  __shared__ __align__(16) short Kt[32][72];      // (key, d)
  __shared__ __align__(16) short Vt[64][40];      // (d, key) transposed
  __shared__ __align__(16) short Pt[4][16][40];   // per-wave (qrow, key)
  int tid = threadIdx.x;
  int lane = tid & 63, w = tid >> 6;
  int quad = lane >> 4, l15 = lane & 15;
  int bh = blockIdx.x >> 5;  // 32 q-tiles per (b,h)
  int qt = blockIdx.x & 31;
  int b = bh >> 4, h = bh & 15;
  int qbase = qt * 64;

  // Q fragments (q already scaled by 1/8): A[m=l15][k=quad*8+j]
  long qoff = ((long)bh * NSEQ + qbase + w * 16 + l15) * HD;
  s8v aq0 = *(const s8v*)&qws[qoff + quad * 8];
  s8v aq1 = *(const s8v*)&qws[qoff + 32 + quad * 8];

  float m_i[4], l_i[4];
  const f4v fz = {0.f, 0.f, 0.f, 0.f};
  f4v o_acc[4];
#pragma unroll
  for (int r = 0; r < 4; r++) { m_i[r] = -1e30f; l_i[r] = 0.f; }
#pragma unroll
  for (int g = 0; g < 4; g++) o_acc[g] = fz;

  int skey = tid >> 3, scg = (tid & 7) * 8;   // K staging: 32 rows x 8 colgroups
  int vkey = tid & 31, vd0 = (tid >> 5) * 8;  // V staging (transposing)

  for (int kb = 0; kb < NSEQ; kb += 32) {
    __syncthreads();
    *(uint4*)&Kt[skey][scg] = *(const uint4*)&kws[((long)bh * NSEQ + kb + skey) * HD + scg];
    {
      union { uint4 u; short s[8]; } c;
      c.u = *(const uint4*)&vws[((long)bh * NSEQ + kb + vkey) * HD + vd0];
#pragma unroll
      for (int i = 0; i < 8; i++) Vt[vd0 + i][vkey] = c.s[i];
    }
    __syncthreads();

    // S = Q @ K^T : per wave 16x32, two 16-col groups
    f4v sc[2];
#pragma unroll
    for (int g = 0; g < 2; g++) {
      s8v bk0 = *(const s8v*)&Kt[g * 16 + l15][quad * 8];
      s8v bk1 = *(const s8v*)&Kt[g * 16 + l15][32 + quad * 8];
      f4v t = __builtin_amdgcn_mfma_f32_16x16x32_bf16(aq0, bk0, fz, 0, 0, 0);
      sc[g] = __builtin_amdgcn_mfma_f32_16x16x32_bf16(aq1, bk1, t, 0, 0, 0);
    }
    float gw0 = gate[b * NSEQ + kb + l15];
    float gw1 = gate[b * NSEQ + kb + 16 + l15];
    float sv[2][4];
#pragma unroll
    for (int r = 0; r < 4; r++) { sv[0][r] = sc[0][r] * gw0; sv[1][r] = sc[1][r] * gw1; }

    // row max across the 16 lanes of each quad
    float tmax[4];
#pragma unroll
    for (int r = 0; r < 4; r++) tmax[r] = fmaxf(sv[0][r], sv[1][r]);
#pragma unroll
    for (int m = 1; m < 16; m <<= 1)
#pragma unroll
      for (int r = 0; r < 4; r++) tmax[r] = fmaxf(tmax[r], __shfl_xor(tmax[r], m));

    float alpha[4], psum[4], p[2][4];
#pragma unroll
    for (int r = 0; r < 4; r++) {
      float mn = fmaxf(m_i[r], tmax[r]);
      alpha[r] = __expf(m_i[r] - mn);
      p[0][r] = __expf(sv[0][r] - mn);
      p[1][r] = __expf(sv[1][r] - mn);
      psum[r] = p[0][r] + p[1][r];
      m_i[r] = mn;
    }
#pragma unroll
    for (int m = 1; m < 16; m <<= 1)
#pragma unroll
      for (int r = 0; r < 4; r++) psum[r] += __shfl_xor(psum[r], m);
#pragma unroll
    for (int r = 0; r < 4; r++) l_i[r] = l_i[r] * alpha[r] + psum[r];
#pragma unroll
    for (int g = 0; g < 4; g++)
#pragma unroll
      for (int r = 0; r < 4; r++) o_acc[g][r] *= alpha[r];

    // P (C-layout) -> per-wave LDS -> A-layout fragment (same-wave DS ops are in-order)
#pragma unroll
    for (int g = 0; g < 2; g++)
#pragma unroll
      for (int r = 0; r < 4; r++)
        Pt[w][quad * 4 + r][g * 16 + l15] = f2bf(p[g][r]);
    s8v ap = *(const s8v*)&Pt[w][l15][quad * 8];

    // O += P @ V : 4 d-groups of 16
#pragma unroll
    for (int g = 0; g < 4; g++) {
      s8v bv = *(const s8v*)&Vt[g * 16 + l15][quad * 8];
      o_acc[g] = __builtin_amdgcn_mfma_f32_16x16x32_bf16(ap, bv, o_acc[g], 0, 0, 0);
    }
  }

  float inv[4];
#pragma unroll
  for (int r = 0; r < 4; r++) inv[r] = 1.f / l_i[r];
#pragma unroll
  for (int g = 0; g < 4; g++)
#pragma unroll
    for (int r = 0; r < 4; r++) {
      int n = qbase + w * 16 + quad * 4 + r;
      int c = h * HD + g * 16 + l15;
      attn_out[((long)b * NSEQ + n) * CDIM + c] = f2bf(o_acc[g][r] * inv[r]);
    }
}

extern "C" void kernel_launch(void* const* d_in, const int* in_sizes, int n_in,
                              void* d_out, int out_size, void* d_ws, size_t ws_size,
                              hipStream_t stream) {
  const float* x     = (const float*)d_in[0];
  const float* mask  = (const float*)d_in[1];
  const float* qkvw  = (const float*)d_in[2];
  const float* qkvb  = (const float*)d_in[3];
  const float* projw = (const float*)d_in[4];
  const float* projb = (const float*)d_in[5];
  const float* g1w   = (const float*)d_in[6];
  const float* g1b   = (const float*)d_in[7];
  const float* g2w   = (const float*)d_in[8];
  const float* g2b   = (const float*)d_in[9];
  float* out = (float*)d_out;

  char* ws = (char*)d_ws;
  short* x_bf    = (short*)(ws);               // 8 MiB
  short* w_qkv   = (short*)(ws + 8388608);     // 6 MiB
  short* w_proj  = (short*)(ws + 14680064);    // 2 MiB
  short* q_ws    = (short*)(ws + 16777216);    // 8 MiB
  short* k_ws    = (short*)(ws + 25165824);    // 8 MiB
  short* v_ws    = (short*)(ws + 33554432);    // 8 MiB
  short* attn_bf = (short*)(ws + 41943040);    // 8 MiB
  float* gate    = (float*)(ws + 50331648);    // 16 KiB

  cvt_kernel<<<4096, 256, 0, stream>>>(x, x_bf, 1048576);
  cvt_kernel<<<3072, 256, 0, stream>>>(qkvw, w_qkv, 786432);
  cvt_kernel<<<1024, 256, 0, stream>>>(projw, w_proj, 262144);
  gate_kernel<<<16, 256, 0, stream>>>(mask, g1w, g1b, g2w, g2b, gate);

  dim3 gq(24, 32);
  gemm_qkv<<<gq, 256, 0, stream>>>(x_bf, w_qkv, qkvb, q_ws, k_ws, v_ws);

  attn_kernel<<<1024, 256, 0, stream>>>(q_ws, k_ws, v_ws, gate, attn_bf);

  dim3 gp(8, 32);
  gemm_proj<<<gp, 256, 0, stream>>>(attn_bf, w_proj, projb, out);
}

// Round 2
// 256.870 us; speedup vs baseline: 1.3391x; 1.3391x over previous
//
#include <hip/hip_runtime.h>

#define H 16
#define NSEQ 2048
#define HD 64
#define CDIM 1024

typedef __attribute__((ext_vector_type(8))) short s8v;
typedef __attribute__((ext_vector_type(4))) float f4v;

#define GLL(g, l) __builtin_amdgcn_global_load_lds( \
    (const __attribute__((address_space(1))) void*)(g), \
    (__attribute__((address_space(3))) void*)(l), 16, 0, 0)

__device__ __forceinline__ short f2bf(float f) {
  union { float f; unsigned u; } x; x.f = f;
  unsigned r = (x.u + 0x7fffu + ((x.u >> 16) & 1u)) >> 16;
  return (short)r;
}

// ---------------- fp32 -> bf16 conversion ----------------
__global__ __launch_bounds__(256) void cvt_kernel(const float* __restrict__ in,
                                                  short* __restrict__ out, int n4) {
  int i = blockIdx.x * 256 + threadIdx.x;
  if (i < n4) {
    float4 f = ((const float4*)in)[i];
    short4 s;
    s.x = f2bf(f.x); s.y = f2bf(f.y); s.z = f2bf(f.z); s.w = f2bf(f.w);
    ((short4*)out)[i] = s;
  }
}

// ---------------- gate MLP ----------------
__global__ __launch_bounds__(256) void gate_kernel(const float* __restrict__ mask,
    const float* __restrict__ g1w, const float* __restrict__ g1b,
    const float* __restrict__ g2w, const float* __restrict__ g2b,
    float* __restrict__ gate) {
  int i = blockIdx.x * 256 + threadIdx.x;  // 4096 = B*N
  float m = mask[i];
  float acc = 0.f;
  for (int j = 0; j < 256; j++) {
    float h = m * g1w[j] + g1b[j];
    h = fmaxf(h, 0.f);
    acc += g2w[j] * h;
  }
  gate[i] = 1.f / (1.f + __expf(-(acc + g2b[0])));
}

// ---------------- QKV GEMM: C[4096,3072] = Xbf @ Wbf^T + bias ----------------
// global_load_lds staging (width 16), XOR-swizzled unpadded 128x32 tiles.
// Epilogue: q scaled by 1/8 into (b,h,n,d); k into (b,h,n,d); v into (b,h,d,n) transposed.
__global__ __launch_bounds__(256) void gemm_qkv(const short* __restrict__ X,
    const short* __restrict__ W, const float* __restrict__ bias,
    short* __restrict__ qws, short* __restrict__ kws, short* __restrict__ vtws) {
  __shared__ __align__(16) short At[4096];
  __shared__ __align__(16) short Bt[4096];
  const int K = CDIM;
  int tid = threadIdx.x;
  int lane = tid & 63, w = tid >> 6;
  int quad = lane >> 4, l15 = lane & 15;
  int wm = w >> 1, wn = w & 1;
  long rowBase = (long)blockIdx.y * 128;
  long colBase = (long)blockIdx.x * 128;
  const f4v fz = {0.f, 0.f, 0.f, 0.f};
  f4v acc[4][4];
#pragma unroll
  for (int i = 0; i < 4; i++)
#pragma unroll
    for (int j = 0; j < 4; j++) acc[i][j] = fz;

  // staging coords for the 2 chunks this thread owns per tile
  int j0 = tid, j1 = 256 + tid;
  int sr0 = j0 >> 2, sp0 = j0 & 3, sc0 = sp0 ^ ((sr0 >> 1) & 3);
  int sr1 = j1 >> 2, sp1 = j1 & 3, sc1 = sp1 ^ ((sr1 >> 1) & 3);
  const short* Xa = X + (rowBase + sr0) * K + sc0 * 8;
  const short* Xb = X + (rowBase + sr1) * K + sc1 * 8;
  const short* Wa = W + (colBase + sr0) * K + sc0 * 8;
  const short* Wb = W + (colBase + sr1) * K + sc1 * 8;

  for (int k0 = 0; k0 < K; k0 += 32) {
    __syncthreads();
    GLL(Xa + k0, &At[j0 * 8]);
    GLL(Xb + k0, &At[j1 * 8]);
    GLL(Wa + k0, &Bt[j0 * 8]);
    GLL(Wb + k0, &Bt[j1 * 8]);
    __syncthreads();
    s8v a[4], b[4];
#pragma unroll
    for (int mi = 0; mi < 4; mi++) {
      int row = wm * 64 + mi * 16 + l15;
      a[mi] = *(const s8v*)&At[row * 32 + ((quad ^ ((row >> 1) & 3)) * 8)];
    }
#pragma unroll
    for (int ni = 0; ni < 4; ni++) {
      int row = wn * 64 + ni * 16 + l15;
      b[ni] = *(const s8v*)&Bt[row * 32 + ((quad ^ ((row >> 1) & 3)) * 8)];
    }
#pragma unroll
    for (int mi = 0; mi < 4; mi++)
#pragma unroll
      for (int ni = 0; ni < 4; ni++)
        acc[mi][ni] = __builtin_amdgcn_mfma_f32_16x16x32_bf16(a[mi], b[ni], acc[mi][ni], 0, 0, 0);
  }
#pragma unroll
  for (int mi = 0; mi < 4; mi++) {
    int row = (int)rowBase + wm * 64 + mi * 16 + quad * 4;
    int bb = row >> 11, nn = row & 2047;
#pragma unroll
    for (int ni = 0; ni < 4; ni++) {
      int col = (int)colBase + wn * 64 + ni * 16 + l15;
      int which = col >> 10, cc = col & 1023;
      int hh = cc >> 6, dd = cc & 63;
      float bcol = bias[col];
      if (which == 2) {
        short4 pv;
        pv.x = f2bf(acc[mi][ni][0] + bcol);
        pv.y = f2bf(acc[mi][ni][1] + bcol);
        pv.z = f2bf(acc[mi][ni][2] + bcol);
        pv.w = f2bf(acc[mi][ni][3] + bcol);
        *(short4*)&vtws[((bb * H + hh) * HD + dd) * NSEQ + nn] = pv;
      } else {
#pragma unroll
        for (int r = 0; r < 4; r++) {
          int idx = ((bb * H + hh) * NSEQ + nn + r) * HD + dd;
          float v = acc[mi][ni][r] + bcol;
          if (which == 0) qws[idx] = f2bf(v * 0.125f);
          else kws[idx] = f2bf(v);
        }
      }
    }
  }
}

// ---------------- Proj GEMM: out[4096,1024] = Abf @ Wbf^T + bias (fp32 out) ----------------
__global__ __launch_bounds__(256) void gemm_proj(const short* __restrict__ X,
    const short* __restrict__ W, const float* __restrict__ bias, float* __restrict__ out) {
  __shared__ __align__(16) short At[4096];
  __shared__ __align__(16) short Bt[4096];
  const int K = CDIM;
  int tid = threadIdx.x;
  int lane = tid & 63, w = tid >> 6;
  int quad = lane >> 4, l15 = lane & 15;
  int wm = w >> 1, wn = w & 1;
  long rowBase = (long)blockIdx.y * 128;
  long colBase = (long)blockIdx.x * 128;
  const f4v fz = {0.f, 0.f, 0.f, 0.f};
  f4v acc[4][4];
#pragma unroll
  for (int i = 0; i < 4; i++)
#pragma unroll
    for (int j = 0; j < 4; j++) acc[i][j] = fz;

  int j0 = tid, j1 = 256 + tid;
  int sr0 = j0 >> 2, sp0 = j0 & 3, sc0 = sp0 ^ ((sr0 >> 1) & 3);
  int sr1 = j1 >> 2, sp1 = j1 & 3, sc1 = sp1 ^ ((sr1 >> 1) & 3);
  const short* Xa = X + (rowBase + sr0) * K + sc0 * 8;
  const short* Xb = X + (rowBase + sr1) * K + sc1 * 8;
  const short* Wa = W + (colBase + sr0) * K + sc0 * 8;
  const short* Wb = W + (colBase + sr1) * K + sc1 * 8;

  for (int k0 = 0; k0 < K; k0 += 32) {
    __syncthreads();
    GLL(Xa + k0, &At[j0 * 8]);
    GLL(Xb + k0, &At[j1 * 8]);
    GLL(Wa + k0, &Bt[j0 * 8]);
    GLL(Wb + k0, &Bt[j1 * 8]);
    __syncthreads();
    s8v a[4], b[4];
#pragma unroll
    for (int mi = 0; mi < 4; mi++) {
      int row = wm * 64 + mi * 16 + l15;
      a[mi] = *(const s8v*)&At[row * 32 + ((quad ^ ((row >> 1) & 3)) * 8)];
    }
#pragma unroll
    for (int ni = 0; ni < 4; ni++) {
      int row = wn * 64 + ni * 16 + l15;
      b[ni] = *(const s8v*)&Bt[row * 32 + ((quad ^ ((row >> 1) & 3)) * 8)];
    }
#pragma unroll
    for (int mi = 0; mi < 4; mi++)
#pragma unroll
      for (int ni = 0; ni < 4; ni++)
        acc[mi][ni] = __builtin_amdgcn_mfma_f32_16x16x32_bf16(a[mi], b[ni], acc[mi][ni], 0, 0, 0);
  }
#pragma unroll
  for (int mi = 0; mi < 4; mi++) {
    int row = (int)rowBase + wm * 64 + mi * 16 + quad * 4;
#pragma unroll
    for (int ni = 0; ni < 4; ni++) {
      int col = (int)colBase + wn * 64 + ni * 16 + l15;
      float bcol = bias[col];
#pragma unroll
      for (int r = 0; r < 4; r++)
        out[(long)(row + r) * CDIM + col] = acc[mi][ni][r] + bcol;
    }
  }
}

// ---------------- Flash attention, no-max softmax, l via MFMA ones-row ----------------
// one block per (b,h,64-row q-tile), BK=32. V pre-transposed (b,h,d,n).
__global__ __launch_bounds__(256) void attn_kernel(const short* __restrict__ qws,
    const short* __restrict__ kws, const short* __restrict__ vtws,
    const float* __restrict__ gate, short* __restrict__ attn_out) {
  __shared__ __align__(16) short Kt[32][72];      // (key, d)
  __shared__ __align__(16) short Vt[80][40];      // (d, key); row 64 = ones, 65..79 = 0
  __shared__ __align__(16) short Pt[4][16][40];   // per-wave (qrow, key)
  int tid = threadIdx.x;
  int lane = tid & 63, w = tid >> 6;
  int quad = lane >> 4, l15 = lane & 15;
  int bh = blockIdx.x >> 5;
  int qt = blockIdx.x & 31;
  int b = bh >> 4, h = bh & 15;
  int qbase = qt * 64;

  // ones row (d=64) and zero rows (65..79) for the l-accumulating 5th MFMA group
  if (tid < 160) {
    int rr = tid / 10, ccs = (tid % 10) * 4;
    short val = (rr == 0) ? (short)0x3F80 : (short)0;
    short4 v4; v4.x = val; v4.y = val; v4.z = val; v4.w = val;
    *(short4*)&Vt[64 + rr][ccs] = v4;
  }

  // Q fragments (q pre-scaled by 1/8): A[m=l15][k=quad*8+j]
  long qoff = ((long)bh * NSEQ + qbase + w * 16 + l15) * HD;
  s8v aq0 = *(const s8v*)&qws[qoff + quad * 8];
  s8v aq1 = *(const s8v*)&qws[qoff + 32 + quad * 8];

  const f4v fz = {0.f, 0.f, 0.f, 0.f};
  f4v o_acc[5];  // 4 d-groups + l accumulator
#pragma unroll
  for (int g = 0; g < 5; g++) o_acc[g] = fz;

  int skey = tid >> 3, scg = (tid & 7) * 8;   // K staging: 32 rows x 8 colgroups
  int vd = tid >> 2, vkg = (tid & 3) * 8;     // V staging: 64 d-rows x 4 keygroups
  const short* kbase = kws + ((long)bh * NSEQ + skey) * HD + scg;
  const short* vbase = vtws + (long)bh * HD * NSEQ + vd * NSEQ + vkg;
  const float* gbase = gate + b * NSEQ + l15;

  for (int kb = 0; kb < NSEQ; kb += 32) {
    __syncthreads();
    *(uint4*)&Kt[skey][scg] = *(const uint4*)&kbase[(long)kb * HD];
    *(uint4*)&Vt[vd][vkg]   = *(const uint4*)&vbase[kb];
    __syncthreads();

    // S = Q @ K^T : per wave 16x32, two 16-col groups
    float p[2][4];
#pragma unroll
    for (int g = 0; g < 2; g++) {
      s8v bk0 = *(const s8v*)&Kt[g * 16 + l15][quad * 8];
      s8v bk1 = *(const s8v*)&Kt[g * 16 + l15][32 + quad * 8];
      f4v t = __builtin_amdgcn_mfma_f32_16x16x32_bf16(aq0, bk0, fz, 0, 0, 0);
      t = __builtin_amdgcn_mfma_f32_16x16x32_bf16(aq1, bk1, t, 0, 0, 0);
      float gw = gbase[kb + g * 16];
#pragma unroll
      for (int r = 0; r < 4; r++) p[g][r] = __expf(t[r] * gw);
    }

    // P (C-layout) -> per-wave LDS -> A-layout fragment
#pragma unroll
    for (int g = 0; g < 2; g++)
#pragma unroll
      for (int r = 0; r < 4; r++)
        Pt[w][quad * 4 + r][g * 16 + l15] = f2bf(p[g][r]);
    s8v ap = *(const s8v*)&Pt[w][l15][quad * 8];

    // O += P @ V (4 d-groups); group 4 accumulates l = P @ ones
#pragma unroll
    for (int g = 0; g < 5; g++) {
      s8v bv = *(const s8v*)&Vt[g * 16 + l15][quad * 8];
      o_acc[g] = __builtin_amdgcn_mfma_f32_16x16x32_bf16(ap, bv, o_acc[g], 0, 0, 0);
    }
  }

  // l for this lane's rows lives at lane quad*16 (col 0 of group 4)
  float inv[4];
#pragma unroll
  for (int r = 0; r < 4; r++) {
    float l = __shfl(o_acc[4][r], quad * 16);
    inv[r] = 1.f / l;
  }
#pragma unroll
  for (int g = 0; g < 4; g++)
#pragma unroll
    for (int r = 0; r < 4; r++) {
      int n = qbase + w * 16 + quad * 4 + r;
      int c = h * HD + g * 16 + l15;
      attn_out[((long)b * NSEQ + n) * CDIM + c] = f2bf(o_acc[g][r] * inv[r]);
    }
}

extern "C" void kernel_launch(void* const* d_in, const int* in_sizes, int n_in,
                              void* d_out, int out_size, void* d_ws, size_t ws_size,
                              hipStream_t stream) {
  const float* x     = (const float*)d_in[0];
  const float* mask  = (const float*)d_in[1];
  const float* qkvw  = (const float*)d_in[2];
  const float* qkvb  = (const float*)d_in[3];
  const float* projw = (const float*)d_in[4];
  const float* projb = (const float*)d_in[5];
  const float* g1w   = (const float*)d_in[6];
  const float* g1b   = (const float*)d_in[7];
  const float* g2w   = (const float*)d_in[8];
  const float* g2b   = (const float*)d_in[9];
  float* out = (float*)d_out;

  char* ws = (char*)d_ws;
  short* x_bf    = (short*)(ws);               // 8 MiB
  short* w_qkv   = (short*)(ws + 8388608);     // 6 MiB
  short* w_proj  = (short*)(ws + 14680064);    // 2 MiB
  short* q_ws    = (short*)(ws + 16777216);    // 8 MiB
  short* k_ws    = (short*)(ws + 25165824);    // 8 MiB
  short* vt_ws   = (short*)(ws + 33554432);    // 8 MiB (transposed: b,h,d,n)
  short* attn_bf = (short*)(ws + 41943040);    // 8 MiB
  float* gate    = (float*)(ws + 50331648);    // 16 KiB

  cvt_kernel<<<4096, 256, 0, stream>>>(x, x_bf, 1048576);
  cvt_kernel<<<3072, 256, 0, stream>>>(qkvw, w_qkv, 786432);
  cvt_kernel<<<1024, 256, 0, stream>>>(projw, w_proj, 262144);
  gate_kernel<<<16, 256, 0, stream>>>(mask, g1w, g1b, g2w, g2b, gate);

  dim3 gq(24, 32);
  gemm_qkv<<<gq, 256, 0, stream>>>(x_bf, w_qkv, qkvb, q_ws, k_ws, vt_ws);

  attn_kernel<<<1024, 256, 0, stream>>>(q_ws, k_ws, vt_ws, gate, attn_bf);

  dim3 gp(8, 32);
  gemm_proj<<<gp, 256, 0, stream>>>(attn_bf, w_proj, projb, out);
}

// Round 3
// 239.645 us; speedup vs baseline: 1.4354x; 1.0719x over previous
//
#include <hip/hip_runtime.h>

#define H 16
#define NSEQ 2048
#define HD 64
#define CDIM 1024

typedef __attribute__((ext_vector_type(8))) short s8v;
typedef __attribute__((ext_vector_type(4))) float f4v;
typedef __attribute__((ext_vector_type(16))) float f16v;

#define GLL(g, l) __builtin_amdgcn_global_load_lds( \
    (const __attribute__((address_space(1))) void*)(g), \
    (__attribute__((address_space(3))) void*)(l), 16, 0, 0)

__device__ __forceinline__ short f2bf(float f) {  // RNE-ish (epilogue use)
  union { float f; unsigned u; } x; x.f = f;
  unsigned r = (x.u + 0x7fffu + ((x.u >> 16) & 1u)) >> 16;
  return (short)r;
}
__device__ __forceinline__ short f2bf_fast(float f) {
  return (short)((__float_as_uint(f) + 0x8000u) >> 16);
}
__device__ __forceinline__ unsigned pk(float a, float b) {  // two bf16 in a dword
  unsigned ua = __float_as_uint(a) + 0x8000u;
  unsigned ub = __float_as_uint(b) + 0x8000u;
  return __builtin_amdgcn_perm(ub, ua, 0x07060302);
}

// ---------------- fused fp32 -> bf16 conversion (x, qkv_w, proj_w) ----------------
__global__ __launch_bounds__(256) void cvt3_kernel(
    const float* __restrict__ a, const float* __restrict__ b, const float* __restrict__ c,
    short* __restrict__ oa, short* __restrict__ ob, short* __restrict__ oc) {
  int i = blockIdx.x * 256 + threadIdx.x;
  const float* src; short* dst; int j;
  if (i < 1048576)      { src = a; dst = oa; j = i; }
  else if (i < 1835008) { src = b; dst = ob; j = i - 1048576; }
  else                  { src = c; dst = oc; j = i - 1835008; }
  float4 f = ((const float4*)src)[j];
  short4 s;
  s.x = f2bf(f.x); s.y = f2bf(f.y); s.z = f2bf(f.z); s.w = f2bf(f.w);
  ((short4*)dst)[j] = s;
}

// ---------------- gate MLP ----------------
__global__ __launch_bounds__(256) void gate_kernel(const float* __restrict__ mask,
    const float* __restrict__ g1w, const float* __restrict__ g1b,
    const float* __restrict__ g2w, const float* __restrict__ g2b,
    float* __restrict__ gate) {
  int i = blockIdx.x * 256 + threadIdx.x;  // 4096 = B*N
  float m = mask[i];
  float acc = 0.f;
  for (int j = 0; j < 256; j++) {
    float h = m * g1w[j] + g1b[j];
    h = fmaxf(h, 0.f);
    acc += g2w[j] * h;
  }
  gate[i] = 1.f / (1.f + __expf(-(acc + g2b[0])));
}

// ---------------- QKV GEMM: C[4096,3072] = Xbf @ Wbf^T + bias ----------------
// Epilogue: q * 1/8 into (b,h,n,d); k * gate[b,n] * log2e into (b,h,n,d); v into (b,h,d,n).
__global__ __launch_bounds__(256) void gemm_qkv(const short* __restrict__ X,
    const short* __restrict__ W, const float* __restrict__ bias, const float* __restrict__ gate,
    short* __restrict__ qws, short* __restrict__ kws, short* __restrict__ vtws) {
  __shared__ __align__(16) short At[4096];
  __shared__ __align__(16) short Bt[4096];
  const int K = CDIM;
  int tid = threadIdx.x;
  int lane = tid & 63, w = tid >> 6;
  int quad = lane >> 4, l15 = lane & 15;
  int wm = w >> 1, wn = w & 1;
  long rowBase = (long)blockIdx.y * 128;
  long colBase = (long)blockIdx.x * 128;
  const f4v fz = {0.f, 0.f, 0.f, 0.f};
  f4v acc[4][4];
#pragma unroll
  for (int i = 0; i < 4; i++)
#pragma unroll
    for (int j = 0; j < 4; j++) acc[i][j] = fz;

  int j0 = tid, j1 = 256 + tid;
  int sr0 = j0 >> 2, sp0 = j0 & 3, sc0 = sp0 ^ ((sr0 >> 1) & 3);
  int sr1 = j1 >> 2, sp1 = j1 & 3, sc1 = sp1 ^ ((sr1 >> 1) & 3);
  const short* Xa = X + (rowBase + sr0) * K + sc0 * 8;
  const short* Xb = X + (rowBase + sr1) * K + sc1 * 8;
  const short* Wa = W + (colBase + sr0) * K + sc0 * 8;
  const short* Wb = W + (colBase + sr1) * K + sc1 * 8;

  for (int k0 = 0; k0 < K; k0 += 32) {
    __syncthreads();
    GLL(Xa + k0, &At[j0 * 8]);
    GLL(Xb + k0, &At[j1 * 8]);
    GLL(Wa + k0, &Bt[j0 * 8]);
    GLL(Wb + k0, &Bt[j1 * 8]);
    __syncthreads();
    s8v a[4], b[4];
#pragma unroll
    for (int mi = 0; mi < 4; mi++) {
      int row = wm * 64 + mi * 16 + l15;
      a[mi] = *(const s8v*)&At[row * 32 + ((quad ^ ((row >> 1) & 3)) * 8)];
    }
#pragma unroll
    for (int ni = 0; ni < 4; ni++) {
      int row = wn * 64 + ni * 16 + l15;
      b[ni] = *(const s8v*)&Bt[row * 32 + ((quad ^ ((row >> 1) & 3)) * 8)];
    }
#pragma unroll
    for (int mi = 0; mi < 4; mi++)
#pragma unroll
      for (int ni = 0; ni < 4; ni++)
        acc[mi][ni] = __builtin_amdgcn_mfma_f32_16x16x32_bf16(a[mi], b[ni], acc[mi][ni], 0, 0, 0);
  }
#pragma unroll
  for (int mi = 0; mi < 4; mi++) {
    int row = (int)rowBase + wm * 64 + mi * 16 + quad * 4;
    int bb = row >> 11, nn = row & 2047;
#pragma unroll
    for (int ni = 0; ni < 4; ni++) {
      int col = (int)colBase + wn * 64 + ni * 16 + l15;
      int which = col >> 10, cc = col & 1023;
      int hh = cc >> 6, dd = cc & 63;
      float bcol = bias[col];
      if (which == 2) {
        short4 pv;
        pv.x = f2bf(acc[mi][ni][0] + bcol);
        pv.y = f2bf(acc[mi][ni][1] + bcol);
        pv.z = f2bf(acc[mi][ni][2] + bcol);
        pv.w = f2bf(acc[mi][ni][3] + bcol);
        *(short4*)&vtws[((bb * H + hh) * HD + dd) * NSEQ + nn] = pv;
      } else {
#pragma unroll
        for (int r = 0; r < 4; r++) {
          int rw = row + r;
          int idx = ((bb * H + hh) * NSEQ + (rw & 2047)) * HD + dd;
          float v = acc[mi][ni][r] + bcol;
          if (which == 0) qws[idx] = f2bf(v * 0.125f);
          else kws[idx] = f2bf(v * (gate[rw] * 1.44269504f));  // gate & log2e folded into K
        }
      }
    }
  }
}

// ---------------- Proj GEMM ----------------
__global__ __launch_bounds__(256) void gemm_proj(const short* __restrict__ X,
    const short* __restrict__ W, const float* __restrict__ bias, float* __restrict__ out) {
  __shared__ __align__(16) short At[4096];
  __shared__ __align__(16) short Bt[4096];
  const int K = CDIM;
  int tid = threadIdx.x;
  int lane = tid & 63, w = tid >> 6;
  int quad = lane >> 4, l15 = lane & 15;
  int wm = w >> 1, wn = w & 1;
  long rowBase = (long)blockIdx.y * 128;
  long colBase = (long)blockIdx.x * 128;
  const f4v fz = {0.f, 0.f, 0.f, 0.f};
  f4v acc[4][4];
#pragma unroll
  for (int i = 0; i < 4; i++)
#pragma unroll
    for (int j = 0; j < 4; j++) acc[i][j] = fz;

  int j0 = tid, j1 = 256 + tid;
  int sr0 = j0 >> 2, sp0 = j0 & 3, sc0 = sp0 ^ ((sr0 >> 1) & 3);
  int sr1 = j1 >> 2, sp1 = j1 & 3, sc1 = sp1 ^ ((sr1 >> 1) & 3);
  const short* Xa = X + (rowBase + sr0) * K + sc0 * 8;
  const short* Xb = X + (rowBase + sr1) * K + sc1 * 8;
  const short* Wa = W + (colBase + sr0) * K + sc0 * 8;
  const short* Wb = W + (colBase + sr1) * K + sc1 * 8;

  for (int k0 = 0; k0 < K; k0 += 32) {
    __syncthreads();
    GLL(Xa + k0, &At[j0 * 8]);
    GLL(Xb + k0, &At[j1 * 8]);
    GLL(Wa + k0, &Bt[j0 * 8]);
    GLL(Wb + k0, &Bt[j1 * 8]);
    __syncthreads();
    s8v a[4], b[4];
#pragma unroll
    for (int mi = 0; mi < 4; mi++) {
      int row = wm * 64 + mi * 16 + l15;
      a[mi] = *(const s8v*)&At[row * 32 + ((quad ^ ((row >> 1) & 3)) * 8)];
    }
#pragma unroll
    for (int ni = 0; ni < 4; ni++) {
      int row = wn * 64 + ni * 16 + l15;
      b[ni] = *(const s8v*)&Bt[row * 32 + ((quad ^ ((row >> 1) & 3)) * 8)];
    }
#pragma unroll
    for (int mi = 0; mi < 4; mi++)
#pragma unroll
      for (int ni = 0; ni < 4; ni++)
        acc[mi][ni] = __builtin_amdgcn_mfma_f32_16x16x32_bf16(a[mi], b[ni], acc[mi][ni], 0, 0, 0);
  }
#pragma unroll
  for (int mi = 0; mi < 4; mi++) {
    int row = (int)rowBase + wm * 64 + mi * 16 + quad * 4;
#pragma unroll
    for (int ni = 0; ni < 4; ni++) {
      int col = (int)colBase + wn * 64 + ni * 16 + l15;
      float bcol = bias[col];
#pragma unroll
      for (int r = 0; r < 4; r++)
        out[(long)(row + r) * CDIM + col] = acc[mi][ni][r] + bcol;
    }
  }
}

// ---------------- Flash attention, 32x32 MFMA, S^T orientation, key-split ----------------
// Block = 128 qrows of one (b,h); 4 waves = (wq 0..1) x (wk 0..1); BK=64 staged, each wave
// handles its 32-key half x its 64 qrows. K pre-scaled by gate*log2e, Q by 1/8 -> p = exp2(s).
// l via 15-add + shfl_xor(32). Key-halves combined via fp32 LDS reduction at the end.
__global__ __launch_bounds__(256, 2) void attn_kernel(const short* __restrict__ qws,
    const short* __restrict__ kws, const short* __restrict__ vtws,
    short* __restrict__ attn_out) {
  __shared__ __align__(16) char smem[36864];
  short* Kt = (short*)smem;              // [64][64] chunk-swizzled (8 KB)
  short* Vt = (short*)(smem + 8192);     // [64][64] chunk-swizzled (8 KB)
  short* Pt = (short*)(smem + 16384);    // [8][32][40] per (wave,rt) (20 KB)
  float* oscr = (float*)smem;            // epilogue alias: [64 d][132 row-pitch] fp32
  float* lscr = (float*)(smem + 33792);  // [2 wk][128 rows]
  float* linv = (float*)(smem + 34816);  // [128 rows]

  int tid = threadIdx.x;
  int lane = tid & 63, w = tid >> 6;
  int l31 = lane & 31, hf = lane >> 5;
  int wq = w >> 1, wk = w & 1;
  int sw = l31 & 7;
  int bh = blockIdx.x >> 4, qt = blockIdx.x & 15;
  int b = bh >> 4, head = bh & 15;
  int qbase = qt * 128;

  // Q B-frags: B[n=qrow=l31][k=d=ds*16+hf*8+j], per (rt, ds)
  s8v qf[2][4];
  {
    const short* qp = qws + ((long)bh * NSEQ + qbase + wq * 64 + l31) * HD + hf * 8;
#pragma unroll
    for (int rt = 0; rt < 2; rt++)
#pragma unroll
      for (int ds = 0; ds < 4; ds++)
        qf[rt][ds] = *(const s8v*)&qp[rt * 32 * HD + ds * 16];
  }

  const f16v fz16 = {0.f,0.f,0.f,0.f,0.f,0.f,0.f,0.f,0.f,0.f,0.f,0.f,0.f,0.f,0.f,0.f};
  f16v oacc[2][2];
#pragma unroll
  for (int rt = 0; rt < 2; rt++)
#pragma unroll
    for (int nt = 0; nt < 2; nt++) oacc[rt][nt] = fz16;
  float l_r[2] = {0.f, 0.f};

  // staging: wave w loads rows [w*16, w*16+16) of K-tile and V-tile (2 GLLs each)
  int r8 = lane >> 3, c8 = lane & 7;
  int row0 = w * 16 + r8, row1 = w * 16 + 8 + r8;
  const short* kg0 = kws + ((long)bh * NSEQ + row0) * HD + (c8 ^ (row0 & 7)) * 8;
  const short* kg1 = kws + ((long)bh * NSEQ + row1) * HD + (c8 ^ (row1 & 7)) * 8;
  const short* vg0 = vtws + ((long)bh * HD + row0) * NSEQ + (c8 ^ (row0 & 7)) * 8;
  const short* vg1 = vtws + ((long)bh * HD + row1) * NSEQ + (c8 ^ (row1 & 7)) * 8;
  short* kl0 = Kt + (w * 16) * 64;
  short* kl1 = Kt + (w * 16 + 8) * 64;
  short* vl0 = Vt + (w * 16) * 64;
  short* vl1 = Vt + (w * 16 + 8) * 64;

  const short* myKrow = Kt + (wk * 32 + l31) * 64;   // A-frag base (key rows)
  short* myP0 = Pt + ((w * 2 + 0) * 32 + l31) * 40;
  short* myP1 = Pt + ((w * 2 + 1) * 32 + l31) * 40;

  for (int kb = 0; kb < NSEQ; kb += 64) {
    __syncthreads();
    GLL(kg0 + (long)kb * HD, kl0);
    GLL(kg1 + (long)kb * HD, kl1);
    GLL(vg0 + kb, vl0);
    GLL(vg1 + kb, vl1);
    __syncthreads();

    // S^T = K' @ Q^T per rt: D[m=key(32, wk half)][n=qrow(32)]
#pragma unroll
    for (int rt = 0; rt < 2; rt++) {
      f16v s = fz16;
#pragma unroll
      for (int ds = 0; ds < 4; ds++) {
        s8v ak = *(const s8v*)&myKrow[((2 * ds + hf) ^ sw) * 8];
        s = __builtin_amdgcn_mfma_f32_32x32x16_bf16(ak, qf[rt][ds], s, 0, 0, 0);
      }
      float p[16];
#pragma unroll
      for (int i = 0; i < 16; i++) p[i] = __builtin_amdgcn_exp2f(s[i]);
      // l partial: sum my 16 keys, then partner half across hf (xor 32)
      float ls = 0.f;
#pragma unroll
      for (int i = 0; i < 16; i++) ls += p[i];
      ls += __shfl_xor(ls, 32);
      l_r[rt] += ls;
      // pack & write P^T -> Pt[qrow=l31][key]: reg quad q covers keys 8q+4hf .. +3
      short* myP = rt ? myP1 : myP0;
#pragma unroll
      for (int q = 0; q < 4; q++) {
        uint2 wv;
        wv.x = pk(p[4 * q], p[4 * q + 1]);
        wv.y = pk(p[4 * q + 2], p[4 * q + 3]);
        *(uint2*)&myP[8 * q + 4 * hf] = wv;
      }
    }
    // O += P @ V : per rt, 2 d-tiles x 2 k-steps (same-wave Pt, no barrier needed)
#pragma unroll
    for (int rt = 0; rt < 2; rt++) {
      short* myP = rt ? myP1 : myP0;
#pragma unroll
      for (int ks = 0; ks < 2; ks++) {
        s8v ap = *(const s8v*)&myP[ks * 16 + hf * 8];
#pragma unroll
        for (int nt = 0; nt < 2; nt++) {
          s8v bv = *(const s8v*)&Vt[(nt * 32 + l31) * 64 + (((4 * wk + 2 * ks + hf) ^ sw) * 8)];
          oacc[rt][nt] = __builtin_amdgcn_mfma_f32_32x32x16_bf16(ap, bv, oacc[rt][nt], 0, 0, 0);
        }
      }
    }
  }

  // ---- combine key halves: wk=1 dumps to LDS, wk=0 reduces + stores ----
  __syncthreads();
  if (wk == 1) {
#pragma unroll
    for (int rt = 0; rt < 2; rt++) {
      lscr[128 + wq * 64 + rt * 32 + l31] = l_r[rt];
#pragma unroll
      for (int nt = 0; nt < 2; nt++)
#pragma unroll
        for (int q = 0; q < 4; q++) {
          f4v t = {oacc[rt][nt][4 * q], oacc[rt][nt][4 * q + 1],
                   oacc[rt][nt][4 * q + 2], oacc[rt][nt][4 * q + 3]};
          *(f4v*)&oscr[(nt * 32 + l31) * 132 + wq * 64 + rt * 32 + 8 * q + 4 * hf] = t;
        }
    }
  } else {
#pragma unroll
    for (int rt = 0; rt < 2; rt++) lscr[wq * 64 + rt * 32 + l31] = l_r[rt];
  }
  __syncthreads();
  if (wk == 0) {
#pragma unroll
    for (int rt = 0; rt < 2; rt++) {
      float lt = l_r[rt] + lscr[128 + wq * 64 + rt * 32 + l31];
      linv[wq * 64 + rt * 32 + l31] = __builtin_amdgcn_rcpf(lt);
    }
#pragma unroll
    for (int rt = 0; rt < 2; rt++)
#pragma unroll
      for (int nt = 0; nt < 2; nt++) {
        int c = head * HD + nt * 32 + l31;
#pragma unroll
        for (int q = 0; q < 4; q++) {
          int rowbase = wq * 64 + rt * 32 + 8 * q + 4 * hf;
          f4v part = *(const f4v*)&oscr[(nt * 32 + l31) * 132 + rowbase];
          f4v li = *(const f4v*)&linv[rowbase];
#pragma unroll
          for (int r = 0; r < 4; r++) {
            float val = (oacc[rt][nt][4 * q + r] + part[r]) * li[r];
            int n = qbase + rowbase + r;
            attn_out[((long)b * NSEQ + n) * CDIM + c] = f2bf_fast(val);
          }
        }
      }
  }
}

extern "C" void kernel_launch(void* const* d_in, const int* in_sizes, int n_in,
                              void* d_out, int out_size, void* d_ws, size_t ws_size,
                              hipStream_t stream) {
  const float* x     = (const float*)d_in[0];
  const float* mask  = (const float*)d_in[1];
  const float* qkvw  = (const float*)d_in[2];
  const float* qkvb  = (const float*)d_in[3];
  const float* projw = (const float*)d_in[4];
  const float* projb = (const float*)d_in[5];
  const float* g1w   = (const float*)d_in[6];
  const float* g1b   = (const float*)d_in[7];
  const float* g2w   = (const float*)d_in[8];
  const float* g2b   = (const float*)d_in[9];
  float* out = (float*)d_out;

  char* ws = (char*)d_ws;
  short* x_bf    = (short*)(ws);               // 8 MiB
  short* w_qkv   = (short*)(ws + 8388608);     // 6 MiB
  short* w_proj  = (short*)(ws + 14680064);    // 2 MiB
  short* q_ws    = (short*)(ws + 16777216);    // 8 MiB
  short* k_ws    = (short*)(ws + 25165824);    // 8 MiB (pre-scaled by gate*log2e)
  short* vt_ws   = (short*)(ws + 33554432);    // 8 MiB (transposed: b,h,d,n)
  short* attn_bf = (short*)(ws + 41943040);    // 8 MiB
  float* gate    = (float*)(ws + 50331648);    // 16 KiB

  cvt3_kernel<<<8192, 256, 0, stream>>>(x, qkvw, projw, x_bf, w_qkv, w_proj);
  gate_kernel<<<16, 256, 0, stream>>>(mask, g1w, g1b, g2w, g2b, gate);

  dim3 gq(24, 32);
  gemm_qkv<<<gq, 256, 0, stream>>>(x_bf, w_qkv, qkvb, gate, q_ws, k_ws, vt_ws);

  attn_kernel<<<512, 256, 0, stream>>>(q_ws, k_ws, vt_ws, attn_bf);

  dim3 gp(8, 32);
  gemm_proj<<<gp, 256, 0, stream>>>(attn_bf, w_proj, projb, out);
}

// Round 4
// 219.276 us; speedup vs baseline: 1.5687x; 1.0929x over previous
//
#include <hip/hip_runtime.h>

#define H 16
#define NSEQ 2048
#define HD 64
#define CDIM 1024

typedef __attribute__((ext_vector_type(8))) short s8v;
typedef __attribute__((ext_vector_type(4))) float f4v;
typedef __attribute__((ext_vector_type(16))) float f16v;

#define GLL(g, l) __builtin_amdgcn_global_load_lds( \
    (const __attribute__((address_space(1))) void*)(g), \
    (__attribute__((address_space(3))) void*)(l), 16, 0, 0)

__device__ __forceinline__ short f2bf(float f) {  // RNE-ish
  union { float f; unsigned u; } x; x.f = f;
  unsigned r = (x.u + 0x7fffu + ((x.u >> 16) & 1u)) >> 16;
  return (short)r;
}
__device__ __forceinline__ short f2bf_fast(float f) {
  return (short)((__float_as_uint(f) + 0x8000u) >> 16);
}
__device__ __forceinline__ unsigned pk(float a, float b) {  // two bf16 in a dword
  unsigned ua = __float_as_uint(a) + 0x8000u;
  unsigned ub = __float_as_uint(b) + 0x8000u;
  return __builtin_amdgcn_perm(ub, ua, 0x07060302);
}

// ---------------- fused fp32->bf16 (x, qkv_w, proj_w) + gate MLP ----------------
__global__ __launch_bounds__(256) void cvt_gate_kernel(
    const float* __restrict__ a, const float* __restrict__ b, const float* __restrict__ c,
    const float* __restrict__ mask,
    const float* __restrict__ g1w, const float* __restrict__ g1b,
    const float* __restrict__ g2w, const float* __restrict__ g2b,
    short* __restrict__ oa, short* __restrict__ ob, short* __restrict__ oc,
    float* __restrict__ gate) {
  int i = blockIdx.x * 256 + threadIdx.x;
  if (i >= 2097152) {  // last 16 blocks: gate MLP for 4096 (b,n)
    int j = i - 2097152;
    float m = mask[j];
    float acc = 0.f;
    for (int k = 0; k < 256; k++) {
      float h = fmaxf(m * g1w[k] + g1b[k], 0.f);
      acc += g2w[k] * h;
    }
    gate[j] = 1.f / (1.f + __expf(-(acc + g2b[0])));
    return;
  }
  const float* src; short* dst; int j;
  if (i < 1048576)      { src = a; dst = oa; j = i; }
  else if (i < 1835008) { src = b; dst = ob; j = i - 1048576; }
  else                  { src = c; dst = oc; j = i - 1835008; }
  float4 f = ((const float4*)src)[j];
  short4 s;
  s.x = f2bf(f.x); s.y = f2bf(f.y); s.z = f2bf(f.z); s.w = f2bf(f.w);
  ((short4*)dst)[j] = s;
}

// ---------------- QKV GEMM: C[4096,3072] = Xbf @ Wbf^T + bias ----------------
// Epilogue: q*1/8 -> (b,h,n,d); k*gate[b,n]*log2e -> (b,h,n,d); v -> (b,h,d,n).
__global__ __launch_bounds__(256) void gemm_qkv(const short* __restrict__ X,
    const short* __restrict__ W, const float* __restrict__ bias, const float* __restrict__ gate,
    short* __restrict__ qws, short* __restrict__ kws, short* __restrict__ vtws) {
  __shared__ __align__(16) short At[4096];
  __shared__ __align__(16) short Bt[4096];
  const int K = CDIM;
  int tid = threadIdx.x;
  int lane = tid & 63, w = tid >> 6;
  int quad = lane >> 4, l15 = lane & 15;
  int wm = w >> 1, wn = w & 1;
  long rowBase = (long)blockIdx.y * 128;
  long colBase = (long)blockIdx.x * 128;
  const f4v fz = {0.f, 0.f, 0.f, 0.f};
  f4v acc[4][4];
#pragma unroll
  for (int i = 0; i < 4; i++)
#pragma unroll
    for (int j = 0; j < 4; j++) acc[i][j] = fz;

  int j0 = tid, j1 = 256 + tid;
  int sr0 = j0 >> 2, sp0 = j0 & 3, sc0 = sp0 ^ ((sr0 >> 1) & 3);
  int sr1 = j1 >> 2, sp1 = j1 & 3, sc1 = sp1 ^ ((sr1 >> 1) & 3);
  const short* Xa = X + (rowBase + sr0) * K + sc0 * 8;
  const short* Xb = X + (rowBase + sr1) * K + sc1 * 8;
  const short* Wa = W + (colBase + sr0) * K + sc0 * 8;
  const short* Wb = W + (colBase + sr1) * K + sc1 * 8;

  for (int k0 = 0; k0 < K; k0 += 32) {
    __syncthreads();
    GLL(Xa + k0, &At[j0 * 8]);
    GLL(Xb + k0, &At[j1 * 8]);
    GLL(Wa + k0, &Bt[j0 * 8]);
    GLL(Wb + k0, &Bt[j1 * 8]);
    __syncthreads();
    s8v a[4], b[4];
#pragma unroll
    for (int mi = 0; mi < 4; mi++) {
      int row = wm * 64 + mi * 16 + l15;
      a[mi] = *(const s8v*)&At[row * 32 + ((quad ^ ((row >> 1) & 3)) * 8)];
    }
#pragma unroll
    for (int ni = 0; ni < 4; ni++) {
      int row = wn * 64 + ni * 16 + l15;
      b[ni] = *(const s8v*)&Bt[row * 32 + ((quad ^ ((row >> 1) & 3)) * 8)];
    }
#pragma unroll
    for (int mi = 0; mi < 4; mi++)
#pragma unroll
      for (int ni = 0; ni < 4; ni++)
        acc[mi][ni] = __builtin_amdgcn_mfma_f32_16x16x32_bf16(a[mi], b[ni], acc[mi][ni], 0, 0, 0);
  }
#pragma unroll
  for (int mi = 0; mi < 4; mi++) {
    int row = (int)rowBase + wm * 64 + mi * 16 + quad * 4;
    int bb = row >> 11, nn = row & 2047;
    f4v g4 = *(const f4v*)&gate[row];   // gate for rows row..row+3
    float gl[4];
#pragma unroll
    for (int r = 0; r < 4; r++) gl[r] = g4[r] * 1.44269504f;
#pragma unroll
    for (int ni = 0; ni < 4; ni++) {
      int col = (int)colBase + wn * 64 + ni * 16 + l15;
      int which = col >> 10, cc = col & 1023;
      int hh = cc >> 6, dd = cc & 63;
      float bcol = bias[col];
      if (which == 2) {
        short4 pv;
        pv.x = f2bf(acc[mi][ni][0] + bcol);
        pv.y = f2bf(acc[mi][ni][1] + bcol);
        pv.z = f2bf(acc[mi][ni][2] + bcol);
        pv.w = f2bf(acc[mi][ni][3] + bcol);
        *(short4*)&vtws[((bb * H + hh) * HD + dd) * NSEQ + nn] = pv;
      } else {
#pragma unroll
        for (int r = 0; r < 4; r++) {
          int idx = ((bb * H + hh) * NSEQ + nn + r) * HD + dd;
          float v = acc[mi][ni][r] + bcol;
          if (which == 0) qws[idx] = f2bf(v * 0.125f);
          else kws[idx] = f2bf(v * gl[r]);  // gate & log2e folded into K
        }
      }
    }
  }
}

// ---------------- Proj GEMM: 64x128 tile (512 blocks = 2/CU) ----------------
__global__ __launch_bounds__(256) void gemm_proj(const short* __restrict__ X,
    const short* __restrict__ W, const float* __restrict__ bias, float* __restrict__ out) {
  __shared__ __align__(16) short At[2048];   // 64 x 32
  __shared__ __align__(16) short Bt[4096];   // 128 x 32
  const int K = CDIM;
  int tid = threadIdx.x;
  int lane = tid & 63, w = tid >> 6;
  int quad = lane >> 4, l15 = lane & 15;
  int wm = w >> 1, wn = w & 1;   // wm: 32-row half, wn: 64-col half
  long rowBase = (long)blockIdx.y * 64;
  long colBase = (long)blockIdx.x * 128;
  const f4v fz = {0.f, 0.f, 0.f, 0.f};
  f4v acc[2][4];
#pragma unroll
  for (int i = 0; i < 2; i++)
#pragma unroll
    for (int j = 0; j < 4; j++) acc[i][j] = fz;

  int j0 = tid, j1 = 256 + tid;
  int sra = j0 >> 2, spa = j0 & 3, sca = spa ^ ((sra >> 1) & 3);     // At: 1 chunk/thread
  int sr0 = j0 >> 2, sp0 = j0 & 3, sc0 = sp0 ^ ((sr0 >> 1) & 3);    // Bt chunk 0
  int sr1 = j1 >> 2, sp1 = j1 & 3, sc1 = sp1 ^ ((sr1 >> 1) & 3);    // Bt chunk 1
  const short* Xa = X + (rowBase + sra) * K + sca * 8;
  const short* Wa = W + (colBase + sr0) * K + sc0 * 8;
  const short* Wb = W + (colBase + sr1) * K + sc1 * 8;

  for (int k0 = 0; k0 < K; k0 += 32) {
    __syncthreads();
    GLL(Xa + k0, &At[j0 * 8]);
    GLL(Wa + k0, &Bt[j0 * 8]);
    GLL(Wb + k0, &Bt[j1 * 8]);
    __syncthreads();
    s8v a[2], b[4];
#pragma unroll
    for (int mi = 0; mi < 2; mi++) {
      int row = wm * 32 + mi * 16 + l15;
      a[mi] = *(const s8v*)&At[row * 32 + ((quad ^ ((row >> 1) & 3)) * 8)];
    }
#pragma unroll
    for (int ni = 0; ni < 4; ni++) {
      int row = wn * 64 + ni * 16 + l15;
      b[ni] = *(const s8v*)&Bt[row * 32 + ((quad ^ ((row >> 1) & 3)) * 8)];
    }
#pragma unroll
    for (int mi = 0; mi < 2; mi++)
#pragma unroll
      for (int ni = 0; ni < 4; ni++)
        acc[mi][ni] = __builtin_amdgcn_mfma_f32_16x16x32_bf16(a[mi], b[ni], acc[mi][ni], 0, 0, 0);
  }
#pragma unroll
  for (int mi = 0; mi < 2; mi++) {
    int row = (int)rowBase + wm * 32 + mi * 16 + quad * 4;
#pragma unroll
    for (int ni = 0; ni < 4; ni++) {
      int col = (int)colBase + wn * 64 + ni * 16 + l15;
      float bcol = bias[col];
#pragma unroll
      for (int r = 0; r < 4; r++)
        out[(long)(row + r) * CDIM + col] = acc[mi][ni][r] + bcol;
    }
  }
}

// ---------------- Flash attention: 64 qrows/block, 4 waves = 2 qtiles x 2 key-halves ----------------
// grid 1024: bh = blockIdx&31 (XCD L2 locality), qt = blockIdx>>5. BK=64.
// K pre-scaled by gate*log2e, Q by 1/8 -> p = exp2(s). No-max softmax; l by 15-add + shfl_xor(32).
__global__ __launch_bounds__(256, 4) void attn_kernel(const short* __restrict__ qws,
    const short* __restrict__ kws, const short* __restrict__ vtws,
    short* __restrict__ attn_out) {
  __shared__ __align__(16) char smem[26624];
  short* Kt = (short*)smem;              // [64][64] chunk-swizzled (8 KB)
  short* Vt = (short*)(smem + 8192);     // [64][64] chunk-swizzled (8 KB)
  short* Pt = (short*)(smem + 16384);    // [4 waves][32][40] (10 KB)
  float* oscr = (float*)smem;            // epilogue alias: [64 d][68 pitch] fp32
  float* lscr = (float*)(smem + 17408);  // [64]
  float* linv = (float*)(smem + 17664);  // [64]

  int tid = threadIdx.x;
  int lane = tid & 63, w = tid >> 6;
  int l31 = lane & 31, hf = lane >> 5;
  int wq = w >> 1, wk = w & 1;
  int sw = l31 & 7;
  int bh = blockIdx.x & 31, qt = blockIdx.x >> 5;
  int b = bh >> 4, head = bh & 15;
  int qbase = qt * 64;

  // Q B-frags: B[n=qrow=l31][k=d]
  s8v qf[4];
  {
    const short* qp = qws + ((long)bh * NSEQ + qbase + wq * 32 + l31) * HD + hf * 8;
#pragma unroll
    for (int ds = 0; ds < 4; ds++) qf[ds] = *(const s8v*)&qp[ds * 16];
  }

  const f16v fz16 = {0.f,0.f,0.f,0.f,0.f,0.f,0.f,0.f,0.f,0.f,0.f,0.f,0.f,0.f,0.f,0.f};
  f16v oacc[2] = {fz16, fz16};
  float l_r = 0.f;

  // staging: wave w loads rows [w*16, w*16+16) of K-tile and V-tile
  int r8 = lane >> 3, c8 = lane & 7;
  int row0 = w * 16 + r8, row1 = row0 + 8;
  const short* kg0 = kws + ((long)bh * NSEQ + row0) * HD + (c8 ^ (row0 & 7)) * 8;
  const short* kg1 = kws + ((long)bh * NSEQ + row1) * HD + (c8 ^ (row1 & 7)) * 8;
  const short* vg0 = vtws + ((long)bh * HD + row0) * NSEQ + (c8 ^ (row0 & 7)) * 8;
  const short* vg1 = vtws + ((long)bh * HD + row1) * NSEQ + (c8 ^ (row1 & 7)) * 8;
  short* kl0 = Kt + (w * 16) * 64;
  short* kl1 = Kt + (w * 16 + 8) * 64;
  short* vl0 = Vt + (w * 16) * 64;
  short* vl1 = Vt + (w * 16 + 8) * 64;

  const short* myKrow = Kt + (wk * 32 + l31) * 64;   // A-frag base (key rows)
  short* myP = Pt + (w * 32 + l31) * 40;

  for (int kb = 0; kb < NSEQ; kb += 64) {
    __syncthreads();
    GLL(kg0 + (long)kb * HD, kl0);
    GLL(kg1 + (long)kb * HD, kl1);
    GLL(vg0 + kb, vl0);
    GLL(vg1 + kb, vl1);
    __syncthreads();

    // S^T = K' @ Q^T : D[m=key(32, wk half)][n=qrow(32, wq tile)]
    f16v s = fz16;
#pragma unroll
    for (int ds = 0; ds < 4; ds++) {
      s8v ak = *(const s8v*)&myKrow[((2 * ds + hf) ^ sw) * 8];
      s = __builtin_amdgcn_mfma_f32_32x32x16_bf16(ak, qf[ds], s, 0, 0, 0);
    }
    float p[16];
#pragma unroll
    for (int i = 0; i < 16; i++) p[i] = __builtin_amdgcn_exp2f(s[i]);
    float ls = 0.f;
#pragma unroll
    for (int i = 0; i < 16; i++) ls += p[i];
    ls += __shfl_xor(ls, 32);
    l_r += ls;
    // pack & write P^T -> Pt[qrow=l31][key]: reg quad q covers keys 8q+4hf..+3
#pragma unroll
    for (int q = 0; q < 4; q++) {
      uint2 wv;
      wv.x = pk(p[4 * q], p[4 * q + 1]);
      wv.y = pk(p[4 * q + 2], p[4 * q + 3]);
      *(uint2*)&myP[8 * q + 4 * hf] = wv;
    }
    // O += P @ V : 2 k-steps x 2 d-tiles (same-wave Pt, no barrier needed)
#pragma unroll
    for (int ks = 0; ks < 2; ks++) {
      s8v ap = *(const s8v*)&myP[ks * 16 + hf * 8];
#pragma unroll
      for (int nt = 0; nt < 2; nt++) {
        s8v bv = *(const s8v*)&Vt[(nt * 32 + l31) * 64 + (((4 * wk + 2 * ks + hf) ^ sw) * 8)];
        oacc[nt] = __builtin_amdgcn_mfma_f32_32x32x16_bf16(ap, bv, oacc[nt], 0, 0, 0);
      }
    }
  }

  // ---- combine key halves: wk=1 dumps to LDS, wk=0 reduces + stores ----
  __syncthreads();
  if (wk == 1) {
    lscr[wq * 32 + l31] = l_r;
#pragma unroll
    for (int nt = 0; nt < 2; nt++)
#pragma unroll
      for (int q = 0; q < 4; q++) {
        f4v t = {oacc[nt][4 * q], oacc[nt][4 * q + 1],
                 oacc[nt][4 * q + 2], oacc[nt][4 * q + 3]};
        *(f4v*)&oscr[(nt * 32 + l31) * 68 + wq * 32 + 8 * q + 4 * hf] = t;
      }
  }
  __syncthreads();
  if (wk == 0) {
    float lt = l_r + lscr[wq * 32 + l31];
    linv[wq * 32 + l31] = __builtin_amdgcn_rcpf(lt);
#pragma unroll
    for (int nt = 0; nt < 2; nt++) {
      int c = head * HD + nt * 32 + l31;
#pragma unroll
      for (int q = 0; q < 4; q++) {
        int rowbase = wq * 32 + 8 * q + 4 * hf;
        f4v part = *(const f4v*)&oscr[(nt * 32 + l31) * 68 + rowbase];
        f4v li = *(const f4v*)&linv[rowbase];
#pragma unroll
        for (int r = 0; r < 4; r++) {
          float val = (oacc[nt][4 * q + r] + part[r]) * li[r];
          int n = qbase + rowbase + r;
          attn_out[((long)b * NSEQ + n) * CDIM + c] = f2bf_fast(val);
        }
      }
    }
  }
}

extern "C" void kernel_launch(void* const* d_in, const int* in_sizes, int n_in,
                              void* d_out, int out_size, void* d_ws, size_t ws_size,
                              hipStream_t stream) {
  const float* x     = (const float*)d_in[0];
  const float* mask  = (const float*)d_in[1];
  const float* qkvw  = (const float*)d_in[2];
  const float* qkvb  = (const float*)d_in[3];
  const float* projw = (const float*)d_in[4];
  const float* projb = (const float*)d_in[5];
  const float* g1w   = (const float*)d_in[6];
  const float* g1b   = (const float*)d_in[7];
  const float* g2w   = (const float*)d_in[8];
  const float* g2b   = (const float*)d_in[9];
  float* out = (float*)d_out;

  char* ws = (char*)d_ws;
  short* x_bf    = (short*)(ws);               // 8 MiB
  short* w_qkv   = (short*)(ws + 8388608);     // 6 MiB
  short* w_proj  = (short*)(ws + 14680064);    // 2 MiB
  short* q_ws    = (short*)(ws + 16777216);    // 8 MiB (pre-scaled by 1/8)
  short* k_ws    = (short*)(ws + 25165824);    // 8 MiB (pre-scaled by gate*log2e)
  short* vt_ws   = (short*)(ws + 33554432);    // 8 MiB (transposed: b,h,d,n)
  short* attn_bf = (short*)(ws + 41943040);    // 8 MiB
  float* gate    = (float*)(ws + 50331648);    // 16 KiB

  cvt_gate_kernel<<<8208, 256, 0, stream>>>(x, qkvw, projw, mask, g1w, g1b, g2w, g2b,
                                            x_bf, w_qkv, w_proj, gate);

  dim3 gq(24, 32);
  gemm_qkv<<<gq, 256, 0, stream>>>(x_bf, w_qkv, qkvb, gate, q_ws, k_ws, vt_ws);

  attn_kernel<<<1024, 256, 0, stream>>>(q_ws, k_ws, vt_ws, attn_bf);

  dim3 gp(8, 64);
  gemm_proj<<<gp, 256, 0, stream>>>(attn_bf, w_proj, projb, out);
}